// Round 1
// baseline (3446.620 us; speedup 1.0000x reference)
//
#include <hip/hip_runtime.h>
#include <cstdint>
#include <cstddef>

#define N_TOK 65536
#define DIM 512
#define FF 2048
#define NE 8

typedef __attribute__((ext_vector_type(8))) short short8;
typedef __attribute__((ext_vector_type(4))) float f32x4;

__device__ __forceinline__ unsigned short f2bf(float f) {
  unsigned u = __builtin_bit_cast(unsigned, f);
  u = u + 0x7fffu + ((u >> 16) & 1u);
  return (unsigned short)(u >> 16);
}

__device__ __forceinline__ void gload_lds16(const void* g, void* l) {
  __builtin_amdgcn_global_load_lds((const __attribute__((address_space(1))) void*)g,
                                   (__attribute__((address_space(3))) void*)l, 16, 0, 0);
}

// ---------------- transpose + cast: in (rows x cols) f32 -> out (cols x rows) bf16, per expert (blockIdx.z)
__global__ __launch_bounds__(256) void k_transpose_cast(
    const float* __restrict__ in, unsigned short* __restrict__ outp, int rows, int cols)
{
  __shared__ float tile[32][33];
  const float* ine = in + (size_t)blockIdx.z * rows * cols;
  unsigned short* oute = outp + (size_t)blockIdx.z * rows * cols;
  int tx = threadIdx.x & 31, ty = threadIdx.x >> 5;
  int r0 = blockIdx.y * 32, c0 = blockIdx.x * 32;
#pragma unroll
  for (int i = 0; i < 4; ++i)
    tile[ty + i*8][tx] = ine[(size_t)(r0 + ty + i*8)*cols + c0 + tx];
  __syncthreads();
#pragma unroll
  for (int i = 0; i < 4; ++i) {
    int r = c0 + ty + i*8, c = r0 + tx;
    oute[(size_t)r*rows + c] = f2bf(tile[tx][ty + i*8]);
  }
}

// ---------------- router: wave per token; fp32 logits, top-2, renorm; cast x -> bf16; build per-expert lists
__global__ __launch_bounds__(256) void k_router(
    const float* __restrict__ x, const float* __restrict__ Wr,
    unsigned short* __restrict__ xb, int* __restrict__ tokl,
    float* __restrict__ pwl, int* __restrict__ cnt)
{
  int lane = threadIdx.x & 63;
  int wv = threadIdx.x >> 6;
  // preload Wr rows [lane*8, lane*8+8): wr[j][e]
  float wr[8][8];
#pragma unroll
  for (int j = 0; j < 8; ++j) {
    const float4* p = (const float4*)(Wr + (size_t)(lane*8 + j)*NE);
    float4 a = p[0], b = p[1];
    wr[j][0]=a.x; wr[j][1]=a.y; wr[j][2]=a.z; wr[j][3]=a.w;
    wr[j][4]=b.x; wr[j][5]=b.y; wr[j][6]=b.z; wr[j][7]=b.w;
  }
  int t0 = blockIdx.x*64 + wv*16;
  for (int it = 0; it < 16; ++it) {
    int t = t0 + it;
    const float4* xp = (const float4*)(x + (size_t)t*DIM + lane*8);
    float4 v0 = xp[0], v1 = xp[1];
    float xv[8] = {v0.x,v0.y,v0.z,v0.w,v1.x,v1.y,v1.z,v1.w};
    // bf16 cast-store (16B per lane, coalesced)
    uint4 pk;
    pk.x = (unsigned)f2bf(xv[0]) | ((unsigned)f2bf(xv[1]) << 16);
    pk.y = (unsigned)f2bf(xv[2]) | ((unsigned)f2bf(xv[3]) << 16);
    pk.z = (unsigned)f2bf(xv[4]) | ((unsigned)f2bf(xv[5]) << 16);
    pk.w = (unsigned)f2bf(xv[6]) | ((unsigned)f2bf(xv[7]) << 16);
    *(uint4*)(xb + (size_t)t*DIM + lane*8) = pk;
    // logits
    float lg[8];
#pragma unroll
    for (int e2 = 0; e2 < 8; ++e2) lg[e2] = 0.f;
#pragma unroll
    for (int j = 0; j < 8; ++j)
#pragma unroll
      for (int e2 = 0; e2 < 8; ++e2) lg[e2] += xv[j]*wr[j][e2];
#pragma unroll
    for (int off = 32; off >= 1; off >>= 1)
#pragma unroll
      for (int e2 = 0; e2 < 8; ++e2) lg[e2] += __shfl_xor(lg[e2], off, 64);
    // top-2 (ties -> lowest index, matching lax.top_k)
    int e0 = 0; float v0m = lg[0];
#pragma unroll
    for (int e2 = 1; e2 < 8; ++e2) if (lg[e2] > v0m) { v0m = lg[e2]; e0 = e2; }
    int e1 = -1; float v1m = -3.0e38f;
#pragma unroll
    for (int e2 = 0; e2 < 8; ++e2) if (e2 != e0 && lg[e2] > v1m) { v1m = lg[e2]; e1 = e2; }
    float w0 = 1.f / (1.f + __expf((v1m - v0m) * 0.4f));   // 1/T = 1/2.5
    float w1 = 1.f - w0;
    if (lane == 0) {
      int p0 = atomicAdd(&cnt[e0], 1);
      tokl[e0*N_TOK + p0] = t; pwl[e0*N_TOK + p0] = w0;
      int p1 = atomicAdd(&cnt[e1], 1);
      tokl[e1*N_TOK + p1] = t; pwl[e1*N_TOK + p1] = w1;
    }
  }
}

// ---------------- fused expert FFN: block = 128 tokens of expert (blockIdx&7); 8 waves x 16 rows each
__global__ __launch_bounds__(512, 2) void k_ffn(
    const unsigned short* __restrict__ xb,
    const unsigned short* __restrict__ w1t,   // (E, F, D) bf16  (W1^T)
    const unsigned short* __restrict__ w2t,   // (E, D, F) bf16  (W2^T)
    const float* __restrict__ b1, const float* __restrict__ b2,
    const int* __restrict__ tokl, const float* __restrict__ pwl,
    const int* __restrict__ cnt, float* __restrict__ out)
{
  int e = blockIdx.x & 7;          // expert <-> XCD affinity under round-robin dispatch
  int tile = blockIdx.x >> 3;
  int count = cnt[e];
  int row0 = tile * 128;
  if (row0 >= count) return;

  __shared__ unsigned short w1s[2][128*64];   // 2 x 16KB, rows f (64B = 8 granules, XOR f&7)
  __shared__ unsigned short w2s[2][512*32];   // 2 x 32KB, rows d (64B = 4 granules, XOR d&3)
  __shared__ unsigned short hs[8][16*128];    // 32KB, wave-private h tiles (granule XOR row)

  int tid = threadIdx.x, lane = tid & 63, wv = tid >> 6;
  int r16 = lane & 15;
  int g4  = lane >> 4;

  // this lane's token row (A operand row for both GEMMs)
  int lrow = row0 + wv*16 + r16;
  int ltok = (lrow < count) ? tokl[e*N_TOK + lrow] : 0;
  const unsigned short* xrow = xb + (size_t)ltok * DIM;

  const unsigned short* w1e = w1t + (size_t)e*FF*DIM;
  const unsigned short* w2e = w2t + (size_t)e*DIM*FF;
  unsigned short* hw = hs[wv];

  const f32x4 fzero = {0.f, 0.f, 0.f, 0.f};
  f32x4 acc[32];
#pragma unroll
  for (int n = 0; n < 32; ++n) acc[n] = fzero;

  int sf  = tid >> 3, sg1 = tid & 7;   // w1 staging: row f = j*64+sf, slot sg1
  int sd  = tid >> 2, sg2 = tid & 3;   // w2 staging: row d = j*128+sd, slot sg2

  auto stage_w1 = [&](int buf, int f0, int kk) {
#pragma unroll
    for (int j = 0; j < 2; ++j) {
      int f = j*64 + sf;
      const unsigned short* src = w1e + (size_t)(f0 + f)*DIM + kk*64 + ((sg1 ^ (f & 7)) * 8);
      gload_lds16(src, &w1s[buf][j*4096 + wv*512]);
    }
  };
  auto stage_w2 = [&](int buf, int fbase) {
#pragma unroll
    for (int j = 0; j < 4; ++j) {
      int d = j*128 + sd;
      const unsigned short* src = w2e + (size_t)d*FF + fbase + ((sg2 ^ (d & 3)) * 8);
      gload_lds16(src, &w2s[buf][j*4096 + wv*512]);
    }
  };

  for (int fi = 0; fi < 16; ++fi) {
    int f0 = fi * 128;
    // ---------- GEMM1: h[16 x 128] = x[16 x 512] @ W1[512 x 128], double-buffered W1^T ----------
    f32x4 hacc[8];
#pragma unroll
    for (int n = 0; n < 8; ++n) hacc[n] = fzero;
    int cur = 0;
    stage_w1(0, f0, 0);
    asm volatile("s_waitcnt vmcnt(0)" ::: "memory");
    __syncthreads();
    for (int kk = 0; kk < 8; ++kk) {
      if (kk < 7) stage_w1(cur ^ 1, f0, kk + 1);
#pragma unroll
      for (int k2 = 0; k2 < 2; ++k2) {
        short8 a = *(const short8*)(xrow + kk*64 + k2*32 + g4*8);
#pragma unroll
        for (int n = 0; n < 8; ++n) {
          int fl = n*16 + r16;
          int p = (k2*4 + g4) ^ (fl & 7);
          short8 bfrag = *(const short8*)&w1s[cur][fl*64 + p*8];
          hacc[n] = __builtin_amdgcn_mfma_f32_16x16x32_bf16(a, bfrag, hacc[n], 0, 0, 0);
        }
      }
      asm volatile("s_waitcnt vmcnt(0)" ::: "memory");
      __syncthreads();
      cur ^= 1;
    }
    // ---------- prefetch first W2 chunk, then bias + gelu + wave-private h store ----------
    stage_w2(0, f0);
#pragma unroll
    for (int n = 0; n < 8; ++n) {
      int col = n*16 + r16;
      float bias = b1[e*FF + f0 + col];
      int gc = col >> 3;
#pragma unroll
      for (int i = 0; i < 4; ++i) {
        int r = g4*4 + i;
        float v = hacc[n][i] + bias;
        float u = 0.7978845608028654f * (v + 0.044715f*v*v*v);
        float g = v / (1.f + __expf(-2.f*u));          // = v*0.5*(1+tanh(u))
        hw[r*128 + ((gc ^ r) * 8) + (col & 7)] = f2bf(g);
      }
    }
    asm volatile("s_waitcnt vmcnt(0)" ::: "memory");
    __syncthreads();
    // ---------- GEMM2: out[16 x 512] += h[16 x 128] @ W2[128 x 512], double-buffered W2^T ----------
    int cur2 = 0;
    for (int ss = 0; ss < 4; ++ss) {
      if (ss < 3) stage_w2(cur2 ^ 1, f0 + (ss + 1)*32);
      short8 a2 = *(const short8*)&hw[r16*128 + (((ss*4 + g4) ^ r16) * 8)];
#pragma unroll
      for (int n = 0; n < 32; ++n) {
        int d = n*16 + r16;
        int p = g4 ^ (d & 3);
        short8 bfrag = *(const short8*)&w2s[cur2][d*32 + p*8];
        acc[n] = __builtin_amdgcn_mfma_f32_16x16x32_bf16(a2, bfrag, acc[n], 0, 0, 0);
      }
      asm volatile("s_waitcnt vmcnt(0)" ::: "memory");
      __syncthreads();
      cur2 ^= 1;
    }
  }

  // ---------- epilogue: weighted atomic scatter-add ----------
  int rb = row0 + wv*16;
  int tk4[4]; float wg4[4]; bool val4[4];
#pragma unroll
  for (int i = 0; i < 4; ++i) {
    int gidx = rb + g4*4 + i;
    val4[i] = (gidx < count);
    tk4[i] = val4[i] ? tokl[e*N_TOK + gidx] : 0;
    wg4[i] = val4[i] ? pwl[e*N_TOK + gidx] : 0.f;
  }
#pragma unroll
  for (int n = 0; n < 32; ++n) {
    int d = n*16 + r16;
    float bias2 = b2[e*DIM + d];
#pragma unroll
    for (int i = 0; i < 4; ++i) {
      if (val4[i]) {
        atomicAdd(out + (size_t)tk4[i]*DIM + d, (acc[n][i] + bias2) * wg4[i]);
      }
    }
  }
}

extern "C" void kernel_launch(void* const* d_in, const int* in_sizes, int n_in,
                              void* d_out, int out_size, void* d_ws, size_t ws_size,
                              hipStream_t stream)
{
  const float* x  = (const float*)d_in[0];
  const float* Wr = (const float*)d_in[1];
  const float* W1 = (const float*)d_in[2];
  const float* b1 = (const float*)d_in[3];
  const float* W2 = (const float*)d_in[4];
  const float* b2 = (const float*)d_in[5];
  float* out = (float*)d_out;
  (void)in_sizes; (void)n_in; (void)ws_size;

  char* ws = (char*)d_ws;
  unsigned short* xb  = (unsigned short*)(ws);                // 64 MB: x bf16
  unsigned short* w1t = (unsigned short*)(ws + 67108864);     // 16 MB: W1^T bf16
  unsigned short* w2t = (unsigned short*)(ws + 83886080);     // 16 MB: W2^T bf16
  int*   tokl = (int*)(ws + 100663296);                       // 2 MB: per-expert token lists
  float* pwl  = (float*)(ws + 102760448);                     // 2 MB: per-expert pair weights
  int*   cnt  = (int*)(ws + 104857600);                       // 32 B: per-expert counts

  hipMemsetAsync(cnt, 0, NE*sizeof(int), stream);
  hipMemsetAsync(d_out, 0, (size_t)out_size*sizeof(float), stream);

  // W1 (E, 512, 2048) -> w1t (E, 2048, 512)
  dim3 g1(FF/32, DIM/32, NE);
  k_transpose_cast<<<g1, 256, 0, stream>>>(W1, w1t, DIM, FF);
  // W2 (E, 2048, 512) -> w2t (E, 512, 2048)
  dim3 g2(DIM/32, FF/32, NE);
  k_transpose_cast<<<g2, 256, 0, stream>>>(W2, w2t, FF, DIM);

  k_router<<<N_TOK/64, 256, 0, stream>>>(x, Wr, xb, tokl, pwl, cnt);

  k_ffn<<<NE * (N_TOK/128), 512, 0, stream>>>(xb, w1t, w2t, b1, b2, tokl, pwl, cnt, out);
}

// Round 2
// 1442.611 us; speedup vs baseline: 2.3892x; 2.3892x over previous
//
#include <hip/hip_runtime.h>
#include <cstdint>
#include <cstddef>

#define N_TOK 65536
#define DIM 512
#define FF 2048
#define NE 8

typedef __attribute__((ext_vector_type(8))) short short8;
typedef __attribute__((ext_vector_type(4))) float f32x4;

__device__ __forceinline__ unsigned short f2bf(float f) {
  unsigned u = __builtin_bit_cast(unsigned, f);
  u = u + 0x7fffu + ((u >> 16) & 1u);
  return (unsigned short)(u >> 16);
}

__device__ __forceinline__ void gload_lds16(const void* g, void* l) {
  __builtin_amdgcn_global_load_lds((const __attribute__((address_space(1))) void*)g,
                                   (__attribute__((address_space(3))) void*)l, 16, 0, 0);
}

#define SBAR __builtin_amdgcn_sched_barrier(0)
// counted-vmcnt barrier: wait own oldest loads, sync, never drain in steady state
#define BARN(N) do { SBAR; \
  asm volatile("s_waitcnt vmcnt(" #N ")" ::: "memory"); \
  __builtin_amdgcn_s_barrier(); SBAR; } while (0)

// ---------------- transpose + cast: in (rows x cols) f32 -> out (cols x rows) bf16, per expert (blockIdx.z)
__global__ __launch_bounds__(256) void k_transpose_cast(
    const float* __restrict__ in, unsigned short* __restrict__ outp, int rows, int cols)
{
  __shared__ float tile[32][33];
  const float* ine = in + (size_t)blockIdx.z * rows * cols;
  unsigned short* oute = outp + (size_t)blockIdx.z * rows * cols;
  int tx = threadIdx.x & 31, ty = threadIdx.x >> 5;
  int r0 = blockIdx.y * 32, c0 = blockIdx.x * 32;
#pragma unroll
  for (int i = 0; i < 4; ++i)
    tile[ty + i*8][tx] = ine[(size_t)(r0 + ty + i*8)*cols + c0 + tx];
  __syncthreads();
#pragma unroll
  for (int i = 0; i < 4; ++i) {
    int r = c0 + ty + i*8, c = r0 + tx;
    oute[(size_t)r*rows + c] = f2bf(tile[tx][ty + i*8]);
  }
}

// ---------------- router: wave per token; block-aggregated expert lists (8 global atomics per block)
__global__ __launch_bounds__(256) void k_router(
    const float* __restrict__ x, const float* __restrict__ Wr,
    unsigned short* __restrict__ xb, int* __restrict__ tokl,
    float* __restrict__ pwl, int* __restrict__ cnt)   // cnt stride 16 ints (64B) per expert
{
  __shared__ int lcnt[8];
  __shared__ int lbase[8];
  __shared__ int ltk[128];
  __shared__ int lslot[128];
  __shared__ float lwt[128];
  __shared__ unsigned char lex[128];

  int tid = threadIdx.x, lane = tid & 63, wv = tid >> 6;
  if (tid < 8) lcnt[tid] = 0;
  // preload Wr rows [lane*8, lane*8+8): wr[j][e]
  float wr[8][8];
#pragma unroll
  for (int j = 0; j < 8; ++j) {
    const float4* p = (const float4*)(Wr + (size_t)(lane*8 + j)*NE);
    float4 a = p[0], b = p[1];
    wr[j][0]=a.x; wr[j][1]=a.y; wr[j][2]=a.z; wr[j][3]=a.w;
    wr[j][4]=b.x; wr[j][5]=b.y; wr[j][6]=b.z; wr[j][7]=b.w;
  }
  __syncthreads();
  int t0 = blockIdx.x*64 + wv*16;
  for (int it = 0; it < 16; ++it) {
    int t = t0 + it;
    const float4* xp = (const float4*)(x + (size_t)t*DIM + lane*8);
    float4 v0 = xp[0], v1 = xp[1];
    float xv[8] = {v0.x,v0.y,v0.z,v0.w,v1.x,v1.y,v1.z,v1.w};
    uint4 pk;
    pk.x = (unsigned)f2bf(xv[0]) | ((unsigned)f2bf(xv[1]) << 16);
    pk.y = (unsigned)f2bf(xv[2]) | ((unsigned)f2bf(xv[3]) << 16);
    pk.z = (unsigned)f2bf(xv[4]) | ((unsigned)f2bf(xv[5]) << 16);
    pk.w = (unsigned)f2bf(xv[6]) | ((unsigned)f2bf(xv[7]) << 16);
    *(uint4*)(xb + (size_t)t*DIM + lane*8) = pk;
    float lg[8];
#pragma unroll
    for (int e2 = 0; e2 < 8; ++e2) lg[e2] = 0.f;
#pragma unroll
    for (int j = 0; j < 8; ++j)
#pragma unroll
      for (int e2 = 0; e2 < 8; ++e2) lg[e2] += xv[j]*wr[j][e2];
#pragma unroll
    for (int off = 32; off >= 1; off >>= 1)
#pragma unroll
      for (int e2 = 0; e2 < 8; ++e2) lg[e2] += __shfl_xor(lg[e2], off, 64);
    // top-2 (ties -> lowest index, matching lax.top_k)
    int e0 = 0; float v0m = lg[0];
#pragma unroll
    for (int e2 = 1; e2 < 8; ++e2) if (lg[e2] > v0m) { v0m = lg[e2]; e0 = e2; }
    int e1 = -1; float v1m = -3.0e38f;
#pragma unroll
    for (int e2 = 0; e2 < 8; ++e2) if (e2 != e0 && lg[e2] > v1m) { v1m = lg[e2]; e1 = e2; }
    float w0 = 1.f / (1.f + __expf((v1m - v0m) * 0.4f));   // 1/T = 1/2.5
    float w1 = 1.f - w0;
    if (lane == 0) {
      int idx = (wv*16 + it) * 2;
      int s0 = atomicAdd(&lcnt[e0], 1);   // LDS atomic
      int s1 = atomicAdd(&lcnt[e1], 1);
      ltk[idx] = t;   lex[idx] = (unsigned char)e0; lwt[idx] = w0; lslot[idx] = s0;
      ltk[idx+1] = t; lex[idx+1] = (unsigned char)e1; lwt[idx+1] = w1; lslot[idx+1] = s1;
    }
  }
  __syncthreads();
  if (tid < 8) lbase[tid] = atomicAdd(&cnt[tid*16], lcnt[tid]);
  __syncthreads();
  if (tid < 128) {
    int e = lex[tid];
    int p = lbase[e] + lslot[tid];
    tokl[e*N_TOK + p] = ltk[tid];
    pwl[e*N_TOK + p]  = lwt[tid];
  }
}

// ---------------- fused expert FFN: block = 128 tokens of expert (blockIdx&7); 8 waves x 16 rows each
// Schedule: counted-vmcnt pipeline. Quantum = 2 vmem ops (one x-prefetch pair OR one 16KB stage).
// GEMM1 phase kk: [XL(kk+1); BARN(4); stage w1(kk+2)->buf (kk+2)%3; 16 MFMA]  (3-buf, distance 2)
// GEMM2 phase c : [BARN(2);  stage w2(c+2)->buf (c+2)%3;           16 MFMA]
// fi-crossing: G1 kk=6/7 stage w2 c0/c1; G2 c=6/7 stage w1(fi+1,0/1) + XL(fi+1,0).
__global__ __launch_bounds__(512, 2) void k_ffn(
    const unsigned short* __restrict__ xb,
    const unsigned short* __restrict__ w1t,   // (E, F, D) bf16  (W1^T)
    const unsigned short* __restrict__ w2t,   // (E, D, F) bf16  (W2^T)
    const float* __restrict__ b1, const float* __restrict__ b2,
    const int* __restrict__ tokl, const float* __restrict__ pwl,
    const int* __restrict__ cnt, float* __restrict__ out)
{
  int e = blockIdx.x & 7;          // expert <-> XCD affinity under round-robin dispatch
  int tile = blockIdx.x >> 3;
  int count = cnt[e*16];
  int row0 = tile * 128;
  if (row0 >= count) return;

  __shared__ unsigned short w1s[3][8192];   // 3 x 16KB: 128 f-rows x 64 K, granule XOR f&7
  __shared__ unsigned short w2s[3][8192];   // 3 x 16KB: 256 d-rows x 32 f, granule XOR d&3
  __shared__ unsigned short hs[8][2048];    // 32KB: wave-private h tiles (granule XOR row)
  __shared__ float b1s[FF];                 // 8KB
  __shared__ float b2s[DIM];                // 2KB

  int tid = threadIdx.x, lane = tid & 63, wv = tid >> 6;
  int r16 = lane & 15;
  int g4  = lane >> 4;

  int lrow = row0 + wv*16 + r16;
  int ltok = (lrow < count) ? tokl[e*N_TOK + lrow] : tokl[e*N_TOK];
  const unsigned short* xrow = xb + (size_t)ltok * DIM;

  const unsigned short* w1e = w1t + (size_t)e*FF*DIM;
  const unsigned short* w2e = w2t + (size_t)e*DIM*FF;
  unsigned short* hw = hs[wv];

  const f32x4 fzero = {0.f, 0.f, 0.f, 0.f};
  f32x4 acc[32];
#pragma unroll
  for (int n = 0; n < 32; ++n) acc[n] = fzero;

  int sf  = tid >> 3, sg1 = tid & 7;   // w1 staging: rows f = j*64+sf, slot sg1
  int sd  = tid >> 2, sg2 = tid & 3;   // w2 staging: rows rr = j*128+sd, slot sg2

  auto stage_w1 = [&](int buf, int f0, int kk) {
#pragma unroll
    for (int j = 0; j < 2; ++j) {
      int f = j*64 + sf;
      const unsigned short* src = w1e + (size_t)(f0 + f)*DIM + kk*64 + ((sg1 ^ (f & 7)) * 8);
      gload_lds16(src, &w1s[buf][j*4096 + wv*512]);
    }
  };
  auto stage_w2 = [&](int buf, int dh, int fbase) {
#pragma unroll
    for (int j = 0; j < 2; ++j) {
      int rr = j*128 + sd;
      const unsigned short* src = w2e + (size_t)(dh*256 + rr)*FF + fbase + ((sg2 ^ (rr & 3)) * 8);
      gload_lds16(src, &w2s[buf][j*4096 + wv*512]);
    }
  };

  // ---- prologue: biases -> LDS, full drain once, then prime the pipeline ----
  gload_lds16(b1 + (size_t)e*FF + tid*4, &b1s[wv*256]);
  if (tid < 128) gload_lds16(b2 + (size_t)e*DIM + tid*4, &b2s[wv*256]);
  BARN(0);

  short8 xa[2][2];
#define XL(kk) do { \
    xa[(kk)&1][0] = *(const short8*)(xrow + (kk)*64 + g4*8); \
    xa[(kk)&1][1] = *(const short8*)(xrow + (kk)*64 + 32 + g4*8); } while (0)

  XL(0);                    // +2   (x(0))
  stage_w1(0, 0, 0);        // +2   (w1 fi0 kk0)
  stage_w1(1, 0, 1);        // +2   (w1 fi0 kk1)

  for (int fi = 0; fi < 16; ++fi) {
    int f0 = fi*128;
    f32x4 hacc[8];
#pragma unroll
    for (int n = 0; n < 8; ++n) hacc[n] = fzero;

    // ---------- GEMM1: h[16x128] = x[16x512] @ W1[512x128] ----------
#pragma unroll
    for (int kk = 0; kk < 8; ++kk) {
      if (kk < 7) XL(kk + 1);                         // +2 pre-barrier (regs, no LDS hazard)
      if (kk < 7) { BARN(4); } else { BARN(2); }      // drain {w1(kk), x(kk)}
      if (kk < 6)       stage_w1((kk+2)%3, f0, kk+2); // +2 post-barrier (WAR-safe)
      else if (kk == 6) stage_w2(0, 0, f0);           // +2  w2 chunk c0
      else              stage_w2(1, 0, f0 + 32);      // +2  w2 chunk c1
      __builtin_amdgcn_s_setprio(1);
#pragma unroll
      for (int k2 = 0; k2 < 2; ++k2) {
        short8 a = xa[kk & 1][k2];
#pragma unroll
        for (int n = 0; n < 8; ++n) {
          int fl = n*16 + r16;
          int p = (k2*4 + g4) ^ (fl & 7);
          short8 bfrag = *(const short8*)&w1s[kk%3][fl*64 + p*8];
          hacc[n] = __builtin_amdgcn_mfma_f32_16x16x32_bf16(a, bfrag, hacc[n], 0, 0, 0);
        }
      }
      __builtin_amdgcn_s_setprio(0);
    }

    // ---------- bias + gelu -> wave-private swizzled h tile (no barrier needed) ----------
#pragma unroll
    for (int n = 0; n < 8; ++n) {
      int col = n*16 + r16;
      float bias = b1s[f0 + col];
      int gc = col >> 3;
#pragma unroll
      for (int i = 0; i < 4; ++i) {
        int r = g4*4 + i;
        float v = hacc[n][i] + bias;
        float u = 0.7978845608028654f * (v + 0.044715f*v*v*v);
        float g = v / (1.f + __expf(-2.f*u));          // = v*0.5*(1+tanh(u))
        hw[r*128 + ((gc ^ r) * 8) + (col & 7)] = f2bf(g);
      }
    }

    // ---------- GEMM2: out[16x512] += h[16x128] @ W2[128x512], 8 chunks (dh,ss) ----------
#pragma unroll
    for (int c = 0; c < 8; ++c) {
      int dh = c >> 2, ss = c & 3;
      if (c == 7 && fi < 15) XL(0);                   // +2 next-fi x(0), pre-barrier
      if (c < 7)            { BARN(2); }              // drain w2(c)
      else if (fi < 15)     { BARN(4); }              // drain w2(7), keep {w1next0, x0}
      else                  { BARN(0); }              // final drain
      if (c < 6)            stage_w2((c+2)%3, (c+2)>>2, f0 + ((c+2)&3)*32);  // +2
      else if (c == 6 && fi < 15) stage_w1(0, f0 + 128, 0);                  // +2
      else if (c == 7 && fi < 15) stage_w1(1, f0 + 128, 1);                  // +2
      short8 a2 = *(const short8*)&hw[r16*128 + (((ss*4 + g4) ^ r16) * 8)];
      __builtin_amdgcn_s_setprio(1);
#pragma unroll
      for (int n = 0; n < 16; ++n) {
        int rr = n*16 + r16;
        int p = g4 ^ (rr & 3);
        short8 bfrag = *(const short8*)&w2s[c%3][rr*32 + p*8];
        acc[dh*16 + n] = __builtin_amdgcn_mfma_f32_16x16x32_bf16(a2, bfrag, acc[dh*16 + n], 0, 0, 0);
      }
      __builtin_amdgcn_s_setprio(0);
    }
  }
#undef XL

  // ---------- epilogue: weighted atomic scatter-add ----------
  int rb = row0 + wv*16;
  int tk4[4]; float wg4[4]; bool val4[4];
#pragma unroll
  for (int i = 0; i < 4; ++i) {
    int gidx = rb + g4*4 + i;
    val4[i] = (gidx < count);
    tk4[i] = val4[i] ? tokl[e*N_TOK + gidx] : 0;
    wg4[i] = val4[i] ? pwl[e*N_TOK + gidx] : 0.f;
  }
#pragma unroll
  for (int m = 0; m < 32; ++m) {
    int d = (m >> 4)*256 + (m & 15)*16 + r16;
    float bias2 = b2s[d];
#pragma unroll
    for (int i = 0; i < 4; ++i) {
      if (val4[i]) {
        atomicAdd(out + (size_t)tk4[i]*DIM + d, (acc[m][i] + bias2) * wg4[i]);
      }
    }
  }
}

extern "C" void kernel_launch(void* const* d_in, const int* in_sizes, int n_in,
                              void* d_out, int out_size, void* d_ws, size_t ws_size,
                              hipStream_t stream)
{
  const float* x  = (const float*)d_in[0];
  const float* Wr = (const float*)d_in[1];
  const float* W1 = (const float*)d_in[2];
  const float* b1 = (const float*)d_in[3];
  const float* W2 = (const float*)d_in[4];
  const float* b2 = (const float*)d_in[5];
  float* out = (float*)d_out;
  (void)in_sizes; (void)n_in; (void)ws_size;

  char* ws = (char*)d_ws;
  unsigned short* xb  = (unsigned short*)(ws);                // 64 MB: x bf16
  unsigned short* w1t = (unsigned short*)(ws + 67108864);     // 16 MB: W1^T bf16
  unsigned short* w2t = (unsigned short*)(ws + 83886080);     // 16 MB: W2^T bf16
  int*   tokl = (int*)(ws + 100663296);                       // 2 MB: per-expert token lists
  float* pwl  = (float*)(ws + 102760448);                     // 2 MB: per-expert pair weights
  int*   cnt  = (int*)(ws + 104857600);                       // 512 B: per-expert counts, stride 16 ints

  hipMemsetAsync(cnt, 0, NE*16*sizeof(int), stream);
  hipMemsetAsync(d_out, 0, (size_t)out_size*sizeof(float), stream);

  // W1 (E, 512, 2048) -> w1t (E, 2048, 512)
  dim3 g1(FF/32, DIM/32, NE);
  k_transpose_cast<<<g1, 256, 0, stream>>>(W1, w1t, DIM, FF);
  // W2 (E, 2048, 512) -> w2t (E, 512, 2048)
  dim3 g2(DIM/32, FF/32, NE);
  k_transpose_cast<<<g2, 256, 0, stream>>>(W2, w2t, FF, DIM);

  k_router<<<N_TOK/64, 256, 0, stream>>>(x, Wr, xb, tokl, pwl, cnt);

  k_ffn<<<NE * (N_TOK/128), 512, 0, stream>>>(xb, w1t, w2t, b1, b2, tokl, pwl, cnt, out);
}